// Round 1
// 293.099 us; speedup vs baseline: 1.3487x; 1.3487x over previous
//
#include <hip/hip_runtime.h>
#include <cstdint>

#define B_SZ 16
#define SEQ 1024
#define DIM 768
#define NH 12
#define HD 64
#define M_TOTAL (B_SZ*SEQ)       // 16384
#define QKV_OUT (3*DIM)          // 2304
#define EXP2_SCALE 0.18033688011f   // (1/8) * log2(e)  -- folded into Q at gemm epilogue

typedef _Float16 f16;
typedef __attribute__((ext_vector_type(8))) f16 f16x8;
typedef __attribute__((ext_vector_type(4))) f16 f16x4;
typedef __attribute__((ext_vector_type(2))) __fp16 pk16x2;   // cvt_pkrtz native type
typedef __attribute__((ext_vector_type(4))) short s4_t;
typedef __attribute__((ext_vector_type(4))) float f32x4;
typedef unsigned int u32;
typedef const __attribute__((address_space(1))) u32* gas_t;
typedef __attribute__((address_space(3))) u32* las_t;

union U4 { pk16x2 h2[2]; f16x4 v; };
union U8 { pk16x2 h2[4]; f16x8 v; };
union HS { f16 h; short s; };

__device__ __forceinline__ void async16(const void* g, void* l) {
    __builtin_amdgcn_global_load_lds((gas_t)g, (las_t)l, 16, 0, 0);
}
__device__ __forceinline__ f32x4 mfma32h(f16x8 a, f16x8 b, f32x4 c) {
    return __builtin_amdgcn_mfma_f32_16x16x32_f16(a, b, c, 0, 0, 0);
}
__device__ __forceinline__ f16x8 ldfragh(const short* p) {
    return *(const f16x8*)p;
}

// ---------------- fp32 -> fp16 conversion of x, w_qkv, w_proj ----------------
__global__ void cvt_kernel(const float* __restrict__ x, const float* __restrict__ wq,
                           const float* __restrict__ wp,
                           short* __restrict__ xb, short* __restrict__ wqb, short* __restrict__ wpb) {
    const long nx = (long)M_TOTAL * DIM / 4;
    const long nq = (long)QKV_OUT * DIM / 4;
    const long np = (long)DIM * DIM / 4;
    const long total = nx + nq + np;
    for (long i = (long)blockIdx.x * blockDim.x + threadIdx.x; i < total;
         i += (long)gridDim.x * blockDim.x) {
        const float4* src; short* dst; long off;
        if (i < nx)            { src = (const float4*)x;  dst = xb;  off = i; }
        else if (i < nx + nq)  { src = (const float4*)wq; dst = wqb; off = i - nx; }
        else                   { src = (const float4*)wp; dst = wpb; off = i - nx - nq; }
        float4 v = src[off];
        U4 u;
        u.h2[0] = __builtin_amdgcn_cvt_pkrtz(v.x, v.y);
        u.h2[1] = __builtin_amdgcn_cvt_pkrtz(v.z, v.w);
        *(f16x4*)(dst + off * 4) = u.v;
    }
}

// ---------------- m97-style f16 GEMM:  C[M,N] = A[M,K] * Bm[N,K]^T ----------------
// EPI 0: scatter to Q/K [b][h][n][hd] and V TRANSPOSED [b][h][hd][n].
//        Q is pre-scaled by EXP2_SCALE so attn's exp2 needs no multiply.
// EPI 1: add bias, write fp32 to Cout [M,N]
template<int EPI, int N, int K>
__global__ __launch_bounds__(256) void gemm_bt(const short* __restrict__ A,
                                               const short* __restrict__ Bm,
                                               short* __restrict__ Cq, short* __restrict__ Ck,
                                               short* __restrict__ Cv,
                                               float* __restrict__ Cout,
                                               const float* __restrict__ bias) {
    __shared__ short As[128 * 32];
    __shared__ short Bs[128 * 32];
    const int tid = threadIdx.x;
    const int w = tid >> 6, l = tid & 63, quad = l >> 4, l15 = l & 15;
    const int wr = w >> 1, wc = w & 1;
    const int m0 = blockIdx.y * 128, n0 = blockIdx.x * 128;

    f32x4 acc[4][4];
#pragma unroll
    for (int i = 0; i < 4; ++i)
#pragma unroll
        for (int j = 0; j < 4; ++j) acc[i][j] = (f32x4){0.f, 0.f, 0.f, 0.f};

    for (int kt = 0; kt < K / 32; ++kt) {
#pragma unroll
        for (int i = 0; i < 2; ++i) {
            int c = i * 256 + tid;
            int row = c >> 2, kc = c & 3;
            async16(&A[(size_t)(m0 + row) * K + kt * 32 + kc * 8], &As[c * 8]);
            async16(&Bm[(size_t)(n0 + row) * K + kt * 32 + kc * 8], &Bs[c * 8]);
        }
        __syncthreads();
        f16x8 af[4], bf[4];
#pragma unroll
        for (int rt = 0; rt < 4; ++rt)
            af[rt] = ldfragh(&As[(wr * 64 + rt * 16 + l15) * 32 + quad * 8]);
#pragma unroll
        for (int ct = 0; ct < 4; ++ct)
            bf[ct] = ldfragh(&Bs[(wc * 64 + ct * 16 + l15) * 32 + quad * 8]);
#pragma unroll
        for (int rt = 0; rt < 4; ++rt)
#pragma unroll
            for (int ct = 0; ct < 4; ++ct)
                acc[rt][ct] = mfma32h(af[rt], bf[ct], acc[rt][ct]);
        __syncthreads();
    }

#pragma unroll
    for (int rt = 0; rt < 4; ++rt) {
#pragma unroll
        for (int ct = 0; ct < 4; ++ct) {
            int col = n0 + wc * 64 + ct * 16 + l15;
            if (EPI == 0) {
                int s = col / DIM;
                int h = (col - s * DIM) >> 6, hd = col & 63;
                int mbase = m0 + wr * 64 + rt * 16 + quad * 4;
                int b = mbase >> 10, nn = mbase & 1023;
                if (s == 2) {
                    // V transposed: [b][h][hd][n]; 4 consecutive n -> one 8B store
                    U4 u;
                    u.h2[0] = __builtin_amdgcn_cvt_pkrtz(acc[rt][ct][0], acc[rt][ct][1]);
                    u.h2[1] = __builtin_amdgcn_cvt_pkrtz(acc[rt][ct][2], acc[rt][ct][3]);
                    *(f16x4*)&Cv[(((size_t)b * NH + h) * HD + hd) * SEQ + nn] = u.v;
                } else {
                    short* dst = (s == 0) ? Cq : Ck;
                    const float qs = (s == 0) ? EXP2_SCALE : 1.0f;
#pragma unroll
                    for (int r = 0; r < 4; ++r) {
                        HS t; t.h = (f16)(acc[rt][ct][r] * qs);
                        dst[(((size_t)b * NH + h) * SEQ + nn + r) * HD + hd] = t.s;
                    }
                }
            } else {
                float bv = bias[col];
#pragma unroll
                for (int r = 0; r < 4; ++r) {
                    int m = m0 + wr * 64 + rt * 16 + quad * 4 + r;
                    Cout[(size_t)m * N + col] = acc[rt][ct][r] + bv;
                }
            }
        }
    }
}

// ---------------- attention: LDS-staged flash, 4-deep async pipeline ----------------
// S^T = K*Q^T trick. kv processed in 32-blocks split into permuted tiles A={8q+j},
// B={8q+4+j}: K rows read from LDS in that order so the S^T output registers
// [uA(4) | uB(4)] form, per lane, the exact 16x16x32 B-fragment (k = quad*8+j) for
// PV -- so PV is 8 x mfma_16x16x32 per block (was 16 x 16x16x16, half-rate shape).
// K+V of each 32-kv block staged ONCE per 4-wave block into LDS via
// global_load_lds (waves previously gathered 4x redundantly from L2).
// 4 LDS buffers, 3-deep prefetch, counted vmcnt + raw s_barrier (T3+T4); LDS
// chunk-XOR swizzle (rule 21: linear DMA dest + pre-swizzled global src + same
// swizzle on ds_read) makes both K and V fragment reads 2-way (= free).
__global__ __launch_bounds__(256) void attn_kernel(const short* __restrict__ Q,
                                                   const short* __restrict__ Km,
                                                   const short* __restrict__ Vt,
                                                   short* __restrict__ O) {
    __shared__ short lds[4][4096];   // per buffer: K 32x64 f16 (2048) | V^T 64x32 f16 (2048)
    const int tid = threadIdx.x;
    const int w = tid >> 6, l = tid & 63, quad = l >> 4, l15 = l & 15;
    const int bid = blockIdx.x;
    const int xcd = bid & 7, kk = bid >> 3;
    const int head = xcd + 8 * (kk >> 3);        // 0..191, 8 q-chunks/head per XCD
    const int q0 = (kk & 7) * 128 + w * 32;      // this wave's 32 q rows
    const int b = head / NH, h = head - b * NH;
    const short* Qp = Q + (size_t)head * (SEQ * HD);
    const short* Kp = Km + (size_t)head * (SEQ * HD);
    const short* Vp = Vt + (size_t)head * (SEQ * HD);   // [hd][n]

    // Q as B-operand fragments: B[n=q=l15][k=hd=quad*8+j]; EXP2_SCALE pre-folded.
    f16x8 qf[2][2];
#pragma unroll
    for (int qt = 0; qt < 2; ++qt)
#pragma unroll
        for (int hf = 0; hf < 2; ++hf)
            qf[qt][hf] = *(const f16x8*)&Qp[(q0 + qt * 16 + l15) * HD + hf * 32 + quad * 8];

    f32x4 oacc[2][4];
#pragma unroll
    for (int qt = 0; qt < 2; ++qt)
#pragma unroll
        for (int ht = 0; ht < 4; ++ht) oacc[qt][ht] = (f32x4){0.f, 0.f, 0.f, 0.f};
    float psum[2] = {0.f, 0.f};

    // ---- staging roles: thread -> one 16B K chunk + one 16B V chunk per kv-block.
    // K buffer: 32 rows x 8 chunks; slot(row,c) holds logical chunk c ^ sK(row),
    //   sK(row) = (row&3) ^ (((row>>3)&3)<<1)   (row&7 of staged rows is always row&3)
    // V buffer: 64 rows x 4 chunks; slot(hd,c) holds logical chunk c ^ ((hd>>1)&3).
    const int kr = tid >> 3, kc = tid & 7;
    const int kcc = kc ^ ((kr & 3) ^ (((kr >> 3) & 3) << 1));
    const short* kSrc = Kp + kr * HD + kcc * 8;     // + g*32*HD per block
    const int kDst = kr * 64 + kc * 8;
    const int vr = tid >> 2, vc = tid & 3;
    const int vcc = vc ^ ((vr >> 1) & 3);
    const short* vSrc = Vp + vr * SEQ + vcc * 8;    // + g*32 per block
    const int vDst = 2048 + vr * 32 + vc * 8;

#define STAGE(bf, g) do {                                   \
        async16(kSrc + (g) * (32 * HD), &lds[bf][kDst]);    \
        async16(vSrc + (g) * 32, &lds[bf][vDst]);           \
    } while (0)

    // ---- swizzled fragment read offsets (shorts) ----
    // K tile A: row rA = 8*(l15>>2)+(l15&3), chunks quad / quad+4; tile B: rows +4
    // (same sK). (c^4) swizzled slot == slot ^ bit2 -> byte-offset ^ 32 shorts.
    const int rA = 8 * (l15 >> 2) + (l15 & 3);
    const int sk = (l15 & 3) ^ ((l15 >> 2) << 1);
    const int offK = rA * 64 + ((quad ^ sk) * 8);
    // V: row hd = ht*16+l15, chunk quad -> slot quad ^ ((l15>>1)&3)  (ht*16>>1 mod 4 == 0)
    const int offV = 2048 + l15 * 32 + ((quad ^ ((l15 >> 1) & 3)) * 8);

    STAGE(0, 0); STAGE(1, 1); STAGE(2, 2);   // 3-deep prologue (6 loads/thread in flight)

    for (int g = 0; g < 32; ++g) {
        // wait for stage g (2 loads/thread/stage; leave later stages in flight)
        if (g <= 29)      asm volatile("s_waitcnt vmcnt(4)" ::: "memory");
        else if (g == 30) asm volatile("s_waitcnt vmcnt(2)" ::: "memory");
        else              asm volatile("s_waitcnt vmcnt(0)" ::: "memory");
        __builtin_amdgcn_s_barrier();
        // buf (g+3)&3 was last read at iter g-1; all its ds_reads drained (lgkmcnt
        // waits precede iter g-1's MFMAs) before any wave passed this barrier.
        if (g < 29) STAGE((g + 3) & 3, g + 3);

        const short* kb = &lds[g & 3][0];
        f16x8 kA0 = ldfragh(kb + offK);
        f16x8 kA1 = ldfragh(kb + (offK ^ 32));
        f16x8 kB0 = ldfragh(kb + offK + 256);
        f16x8 kB1 = ldfragh(kb + (offK ^ 32) + 256);
        f16x8 v0 = ldfragh(kb + offV);
        f16x8 v1 = ldfragh(kb + offV + 512);
        f16x8 v2 = ldfragh(kb + offV + 1024);
        f16x8 v3 = ldfragh(kb + offV + 1536);

        __builtin_amdgcn_s_setprio(1);
#pragma unroll
        for (int qt = 0; qt < 2; ++qt) {
            f32x4 sA = (f32x4){0.f, 0.f, 0.f, 0.f};
            sA = mfma32h(kA0, qf[qt][0], sA);
            sA = mfma32h(kA1, qf[qt][1], sA);
            f32x4 sB = (f32x4){0.f, 0.f, 0.f, 0.f};
            sB = mfma32h(kB0, qf[qt][0], sB);
            sB = mfma32h(kB1, qf[qt][1], sB);
            float eA0 = __builtin_amdgcn_exp2f(sA[0]);
            float eA1 = __builtin_amdgcn_exp2f(sA[1]);
            float eA2 = __builtin_amdgcn_exp2f(sA[2]);
            float eA3 = __builtin_amdgcn_exp2f(sA[3]);
            float eB0 = __builtin_amdgcn_exp2f(sB[0]);
            float eB1 = __builtin_amdgcn_exp2f(sB[1]);
            float eB2 = __builtin_amdgcn_exp2f(sB[2]);
            float eB3 = __builtin_amdgcn_exp2f(sB[3]);
            psum[qt] += ((eA0 + eA1) + (eA2 + eA3)) + ((eB0 + eB1) + (eB2 + eB3));
            // [uA | uB] = P^T B-fragment for 16x16x32: element j <-> kv = quad*8 + j
            U8 u;
            u.h2[0] = __builtin_amdgcn_cvt_pkrtz(eA0, eA1);
            u.h2[1] = __builtin_amdgcn_cvt_pkrtz(eA2, eA3);
            u.h2[2] = __builtin_amdgcn_cvt_pkrtz(eB0, eB1);
            u.h2[3] = __builtin_amdgcn_cvt_pkrtz(eB2, eB3);
            oacc[qt][0] = mfma32h(v0, u.v, oacc[qt][0]);
            oacc[qt][1] = mfma32h(v1, u.v, oacc[qt][1]);
            oacc[qt][2] = mfma32h(v2, u.v, oacc[qt][2]);
            oacc[qt][3] = mfma32h(v3, u.v, oacc[qt][3]);
        }
        __builtin_amdgcn_s_setprio(0);
    }
#undef STAGE

    // full row sums: reduce partials across the 4 quads (lanes differing in bits 4,5)
#pragma unroll
    for (int qt = 0; qt < 2; ++qt) {
        psum[qt] += __shfl_xor(psum[qt], 16);
        psum[qt] += __shfl_xor(psum[qt], 32);
    }

    // epilogue: lane holds O[q=l15][hd=ht*16+quad*4+r] -> four 8B stores per q-tile
#pragma unroll
    for (int qt = 0; qt < 2; ++qt) {
        float rinv = 1.0f / psum[qt];
        short* orow = &O[((size_t)b * SEQ + q0 + qt * 16 + l15) * DIM + h * HD + quad * 4];
#pragma unroll
        for (int ht = 0; ht < 4; ++ht) {
            U4 u;
            u.h2[0] = __builtin_amdgcn_cvt_pkrtz(oacc[qt][ht][0] * rinv, oacc[qt][ht][1] * rinv);
            u.h2[1] = __builtin_amdgcn_cvt_pkrtz(oacc[qt][ht][2] * rinv, oacc[qt][ht][3] * rinv);
            *(f16x4*)(orow + ht * 16) = u.v;
        }
    }
}

extern "C" void kernel_launch(void* const* d_in, const int* in_sizes, int n_in,
                              void* d_out, int out_size, void* d_ws, size_t ws_size,
                              hipStream_t stream) {
    const float* x      = (const float*)d_in[0];
    const float* w_qkv  = (const float*)d_in[1];
    const float* w_proj = (const float*)d_in[2];
    const float* b_proj = (const float*)d_in[3];
    float* out = (float*)d_out;

    short* p = (short*)d_ws;
    short* Xb  = p; p += (size_t)M_TOTAL * DIM;
    short* Wqb = p; p += (size_t)QKV_OUT * DIM;
    short* Wpb = p; p += (size_t)DIM * DIM;
    short* Qb  = p; p += (size_t)B_SZ * NH * SEQ * HD;
    short* Kb  = p; p += (size_t)B_SZ * NH * SEQ * HD;
    short* Vtb = p; p += (size_t)B_SZ * NH * SEQ * HD;   // transposed [b][h][hd][n]
    short* Ob  = p; p += (size_t)M_TOTAL * DIM;

    cvt_kernel<<<1024, 256, 0, stream>>>(x, w_qkv, w_proj, Xb, Wqb, Wpb);
    gemm_bt<0, QKV_OUT, DIM><<<dim3(QKV_OUT / 128, M_TOTAL / 128), 256, 0, stream>>>(
        Xb, Wqb, Qb, Kb, Vtb, nullptr, nullptr);
    attn_kernel<<<B_SZ * NH * (SEQ / 128), 256, 0, stream>>>(Qb, Kb, Vtb, Ob);
    gemm_bt<1, DIM, DIM><<<dim3(DIM / 128, M_TOTAL / 128), 256, 0, stream>>>(
        Ob, Wpb, nullptr, nullptr, nullptr, out, b_proj);
}

// Round 2
// 273.567 us; speedup vs baseline: 1.4450x; 1.0714x over previous
//
#include <hip/hip_runtime.h>
#include <cstdint>

#define B_SZ 16
#define SEQ 1024
#define DIM 768
#define NH 12
#define HD 64
#define M_TOTAL (B_SZ*SEQ)       // 16384
#define QKV_OUT (3*DIM)          // 2304
#define EXP2_SCALE 0.18033688011f   // (1/8) * log2(e)  -- folded into Q at gemm epilogue

typedef _Float16 f16;
typedef __attribute__((ext_vector_type(8))) f16 f16x8;
typedef __attribute__((ext_vector_type(4))) f16 f16x4;
typedef __attribute__((ext_vector_type(2))) __fp16 pk16x2;   // cvt_pkrtz native type
typedef __attribute__((ext_vector_type(4))) short s4_t;
typedef __attribute__((ext_vector_type(4))) float f32x4;
typedef unsigned int u32;
typedef const __attribute__((address_space(1))) u32* gas_t;
typedef __attribute__((address_space(3))) u32* las_t;

union U4 { pk16x2 h2[2]; f16x4 v; };
union U8 { pk16x2 h2[4]; f16x8 v; };
union HS { f16 h; short s; };

__device__ __forceinline__ void async16(const void* g, void* l) {
    __builtin_amdgcn_global_load_lds((gas_t)g, (las_t)l, 16, 0, 0);
}
__device__ __forceinline__ f32x4 mfma32h(f16x8 a, f16x8 b, f32x4 c) {
    return __builtin_amdgcn_mfma_f32_16x16x32_f16(a, b, c, 0, 0, 0);
}
__device__ __forceinline__ f16x8 ldfragh(const short* p) {
    return *(const f16x8*)p;
}

// ---------------- fp32 -> fp16 conversion of x, w_qkv, w_proj ----------------
__global__ void cvt_kernel(const float* __restrict__ x, const float* __restrict__ wq,
                           const float* __restrict__ wp,
                           short* __restrict__ xb, short* __restrict__ wqb, short* __restrict__ wpb) {
    const long nx = (long)M_TOTAL * DIM / 4;
    const long nq = (long)QKV_OUT * DIM / 4;
    const long np = (long)DIM * DIM / 4;
    const long total = nx + nq + np;
    for (long i = (long)blockIdx.x * blockDim.x + threadIdx.x; i < total;
         i += (long)gridDim.x * blockDim.x) {
        const float4* src; short* dst; long off;
        if (i < nx)            { src = (const float4*)x;  dst = xb;  off = i; }
        else if (i < nx + nq)  { src = (const float4*)wq; dst = wqb; off = i - nx; }
        else                   { src = (const float4*)wp; dst = wpb; off = i - nx - nq; }
        float4 v = src[off];
        U4 u;
        u.h2[0] = __builtin_amdgcn_cvt_pkrtz(v.x, v.y);
        u.h2[1] = __builtin_amdgcn_cvt_pkrtz(v.z, v.w);
        *(f16x4*)(dst + off * 4) = u.v;
    }
}

// one C-quadrant (64 rows x 32 cols per wave) x K=64: 16 MFMA
template<int QM, int QN>
__device__ __forceinline__ void mfma_quad(f32x4 (&acc)[8][4], const f16x8 (&af)[4][2],
                                          const f16x8 (&bf)[4][2]) {
#pragma unroll
    for (int r = 0; r < 4; ++r)
#pragma unroll
        for (int c = 0; c < 2; ++c) {
            f32x4 t = acc[QM * 4 + r][QN * 2 + c];
            t = mfma32h(af[r][0], bf[QN * 2 + c][0], t);
            t = mfma32h(af[r][1], bf[QN * 2 + c][1], t);
            acc[QM * 4 + r][QN * 2 + c] = t;
        }
}

// ---------------- 256x256-tile 8-phase f16 GEMM:  C[M,N] = A[M,K] * Bm[N,K]^T ----------
// 8 waves (2M x 4N), per-wave 128x64 output, BK=64, 2 LDS K-tile slots (128 KiB).
// Schedule (T3+T4): tile t computed at global phases 4t+1..4t+4 (quadrants
// (mh,nh) = 00,01,10,11); its 4 half-tiles (Bl,Bh,Al,Ah) staged at phases
// 4t-5..4t-2 -- exactly after the previous tenant's reads of that region end
// (B free after 4t-6, A after 4t-5). vmcnt(4) at phases 4 and 8 guarantees the
// next tile landed while 2 half-tiles stay in flight (never drain mid-loop).
// T2 swizzle both-sides (rule 21): logical chunk c of row r lives at LDS slot
// c^(r&7); DMA dest linear, global SOURCE pre-swizzled, ds_read applies same XOR
// -> fragment reads conflict-free. T5 setprio around each 16-MFMA cluster.
// EPI 0: scatter to Q/K [b][h][n][hd] (Q pre-scaled by EXP2_SCALE) and V^T [b][h][hd][n]
// EPI 1: add bias, write fp32 to Cout [M,N]
template<int EPI, int N, int K>
__global__ __launch_bounds__(512, 2) void gemm_bt(const short* __restrict__ A,
                                                  const short* __restrict__ Bm,
                                                  short* __restrict__ Cq, short* __restrict__ Ck,
                                                  short* __restrict__ Cv,
                                                  float* __restrict__ Cout,
                                                  const float* __restrict__ bias) {
    static_assert(K % 128 == 0, "even K-tile count required");
    constexpr int NT = K / 64;       // K-tiles
    constexpr int NIT = NT / 2;      // iterations (2 tiles each)
    __shared__ short lds[65536];     // 128 KiB: 2 slots x (A[256][64] | B[256][64])

    const int tid = threadIdx.x;
    const int l = tid & 63, quad = l >> 4, l15 = l & 15, l7 = l15 & 7;
    const int w = tid >> 6, wr = w >> 2, wc = w & 3;

    // bijective XCD swizzle (nwg % 8 == 0 for both instantiations: 576, 192)
    const int gx = gridDim.x;
    const int nwg = gx * (int)gridDim.y;
    int fid = (int)blockIdx.y * gx + (int)blockIdx.x;
    fid = (fid & 7) * (nwg >> 3) + (fid >> 3);
    const int m0 = (fid / gx) * 256;
    const int n0 = (fid % gx) * 256;

    // staging roles: 512 threads x 2 loads cover one 128x64 half-tile (16 KB).
    // chunk ci = j*512+tid -> (row=ci>>3, slot sc=ci&7); logical chunk = sc^(row&7).
    const int srow = tid >> 3, sc = tid & 7;
    const int scc = sc ^ (srow & 7);            // (row+64)&7 == row&7, same for j=0,1
    const short* Asrc = A + (size_t)(m0 + srow) * K + scc * 8;
    const short* Bsrc = Bm + (size_t)(n0 + srow) * K + scc * 8;
    const int sdst = srow * 64 + sc * 8;

#define STAGE_A(t, hi) do {                                              \
        const int sb_ = ((t) & 1) * 32768 + (hi) * 8192;                 \
        const size_t go_ = (size_t)((hi) * 128) * K + (size_t)(t) * 64;  \
        async16(Asrc + go_, &lds[sb_ + sdst]);                           \
        async16(Asrc + go_ + (size_t)64 * K, &lds[sb_ + sdst + 4096]);   \
    } while (0)
#define STAGE_B(t, hi) do {                                              \
        const int sb_ = ((t) & 1) * 32768 + 16384 + (hi) * 8192;         \
        const size_t go_ = (size_t)((hi) * 128) * K + (size_t)(t) * 64;  \
        async16(Bsrc + go_, &lds[sb_ + sdst]);                           \
        async16(Bsrc + go_ + (size_t)64 * K, &lds[sb_ + sdst + 4096]);   \
    } while (0)

    // fragment read offsets (shorts); swizzled chunk = (kh*4+quad)^(row&7), row&7==l7
    const int aoff = wr * 8192 + l15 * 64;
    const int boff = 16384 + wc * 4096 + l15 * 64;
    const int c0 = (quad ^ l7) * 8;
    const int c1 = ((4 + quad) ^ l7) * 8;

#define RD_A(SB, MHALF) do {                                                                  \
        const int ab_ = (SB) + aoff + (MHALF) * 4096;                                         \
        af[0][0] = ldfragh(&lds[ab_ + c0]);        af[0][1] = ldfragh(&lds[ab_ + c1]);        \
        af[1][0] = ldfragh(&lds[ab_ + 1024 + c0]); af[1][1] = ldfragh(&lds[ab_ + 1024 + c1]); \
        af[2][0] = ldfragh(&lds[ab_ + 2048 + c0]); af[2][1] = ldfragh(&lds[ab_ + 2048 + c1]); \
        af[3][0] = ldfragh(&lds[ab_ + 3072 + c0]); af[3][1] = ldfragh(&lds[ab_ + 3072 + c1]); \
    } while (0)
#define RD_B(SB, NHALF) do {                                                                             \
        const int bb_ = (SB) + boff + (NHALF) * 2048;                                                    \
        bf[(NHALF)*2][0]   = ldfragh(&lds[bb_ + c0]);        bf[(NHALF)*2][1]   = ldfragh(&lds[bb_ + c1]);        \
        bf[(NHALF)*2+1][0] = ldfragh(&lds[bb_ + 1024 + c0]); bf[(NHALF)*2+1][1] = ldfragh(&lds[bb_ + 1024 + c1]); \
    } while (0)

#define BAR1() __builtin_amdgcn_s_barrier()
#define BAR2() do { __builtin_amdgcn_s_barrier(); __builtin_amdgcn_sched_barrier(0); } while (0)
#define VMC4() asm volatile("s_waitcnt vmcnt(4)" ::: "memory")
#define VMC0() asm volatile("s_waitcnt vmcnt(0)" ::: "memory")
#define MQ(QM, QN) do {                                        \
        __builtin_amdgcn_s_setprio(1);                         \
        mfma_quad<QM, QN>(acc, af, bf);                        \
        __builtin_amdgcn_s_setprio(0);                         \
    } while (0)

    f32x4 acc[8][4];
#pragma unroll
    for (int i = 0; i < 8; ++i)
#pragma unroll
        for (int j = 0; j < 4; ++j) acc[i][j] = (f32x4){0.f, 0.f, 0.f, 0.f};
    f16x8 af[4][2], bf[4][2];

    // prologue: tile 0 fully + tile 1 B-halves (12 loads); tile 0 landed, 4 in flight
    STAGE_B(0, 0); STAGE_B(0, 1); STAGE_A(0, 0); STAGE_A(0, 1);
    STAGE_B(1, 0); STAGE_B(1, 1);
    VMC4();
    BAR2();

    for (int i = 0; i < NIT; ++i) {
        const int to = 2 * i + 1, t2 = 2 * i + 2, t3 = 2 * i + 3;
        // ---------------- tile 2i (slot 0) ----------------
        RD_A(0, 0); RD_B(0, 0);          // ph1 (mh0,nh0)
        STAGE_A(to, 0);
        BAR1(); MQ(0, 0); BAR2();

        RD_B(0, 1);                      // ph2 (mh0,nh1)
        STAGE_A(to, 1);
        BAR1(); MQ(0, 1); BAR2();

        RD_A(0, 1);                      // ph3 (mh1,nh0)
        if (t2 < NT) STAGE_B(t2, 0);
        BAR1(); MQ(1, 0); BAR2();

        if (t2 < NT) STAGE_B(t2, 1);     // ph4 (mh1,nh1)
        BAR1(); MQ(1, 1);
        if (i == NIT - 1) VMC0(); else VMC4();   // tile 2i+1 landed
        BAR2();

        // ---------------- tile 2i+1 (slot 1) ----------------
        RD_A(32768, 0); RD_B(32768, 0);  // ph5
        if (t2 < NT) STAGE_A(t2, 0);
        BAR1(); MQ(0, 0); BAR2();

        RD_B(32768, 1);                  // ph6
        if (t2 < NT) STAGE_A(t2, 1);
        BAR1(); MQ(0, 1); BAR2();

        RD_A(32768, 1);                  // ph7
        if (t3 < NT) STAGE_B(t3, 0);
        BAR1(); MQ(1, 0); BAR2();

        if (t3 < NT) STAGE_B(t3, 1);     // ph8
        BAR1(); MQ(1, 1);
        if (i == NIT - 1) VMC0(); else VMC4();   // tile 2i+2 landed
        BAR2();
    }
#undef STAGE_A
#undef STAGE_B
#undef RD_A
#undef RD_B

    // epilogue: acc[rt][ct] covers rows (rt>>2)*64+(rt&3)*16, cols (ct>>1)*32+(ct&1)*16
#pragma unroll
    for (int rt = 0; rt < 8; ++rt) {
        const int mrow = m0 + wr * 128 + (rt >> 2) * 64 + (rt & 3) * 16 + quad * 4;
#pragma unroll
        for (int ct = 0; ct < 4; ++ct) {
            const int col = n0 + wc * 64 + (ct >> 1) * 32 + (ct & 1) * 16 + l15;
            if (EPI == 0) {
                int s = col / DIM;
                int h = (col - s * DIM) >> 6, hd = col & 63;
                int b = mrow >> 10, nn = mrow & 1023;
                if (s == 2) {
                    // V transposed: [b][h][hd][n]; 4 consecutive n -> one 8B store
                    U4 u;
                    u.h2[0] = __builtin_amdgcn_cvt_pkrtz(acc[rt][ct][0], acc[rt][ct][1]);
                    u.h2[1] = __builtin_amdgcn_cvt_pkrtz(acc[rt][ct][2], acc[rt][ct][3]);
                    *(f16x4*)&Cv[(((size_t)b * NH + h) * HD + hd) * SEQ + nn] = u.v;
                } else {
                    short* dst = (s == 0) ? Cq : Ck;
                    const float qs = (s == 0) ? EXP2_SCALE : 1.0f;
#pragma unroll
                    for (int r = 0; r < 4; ++r) {
                        HS t; t.h = (f16)(acc[rt][ct][r] * qs);
                        dst[(((size_t)b * NH + h) * SEQ + nn + r) * HD + hd] = t.s;
                    }
                }
            } else {
                float bv = bias[col];
#pragma unroll
                for (int r = 0; r < 4; ++r)
                    Cout[(size_t)(mrow + r) * N + col] = acc[rt][ct][r] + bv;
            }
        }
    }
}

// ---------------- attention: LDS-staged flash, 4-deep async pipeline ----------------
// (unchanged from previous round -- verified, ~halved vs register-gather version)
__global__ __launch_bounds__(256) void attn_kernel(const short* __restrict__ Q,
                                                   const short* __restrict__ Km,
                                                   const short* __restrict__ Vt,
                                                   short* __restrict__ O) {
    __shared__ short lds[4][4096];   // per buffer: K 32x64 f16 (2048) | V^T 64x32 f16 (2048)
    const int tid = threadIdx.x;
    const int w = tid >> 6, l = tid & 63, quad = l >> 4, l15 = l & 15;
    const int bid = blockIdx.x;
    const int xcd = bid & 7, kk = bid >> 3;
    const int head = xcd + 8 * (kk >> 3);        // 0..191, 8 q-chunks/head per XCD
    const int q0 = (kk & 7) * 128 + w * 32;      // this wave's 32 q rows
    const int b = head / NH, h = head - b * NH;
    const short* Qp = Q + (size_t)head * (SEQ * HD);
    const short* Kp = Km + (size_t)head * (SEQ * HD);
    const short* Vp = Vt + (size_t)head * (SEQ * HD);   // [hd][n]

    // Q as B-operand fragments: B[n=q=l15][k=hd=quad*8+j]; EXP2_SCALE pre-folded.
    f16x8 qf[2][2];
#pragma unroll
    for (int qt = 0; qt < 2; ++qt)
#pragma unroll
        for (int hf = 0; hf < 2; ++hf)
            qf[qt][hf] = *(const f16x8*)&Qp[(q0 + qt * 16 + l15) * HD + hf * 32 + quad * 8];

    f32x4 oacc[2][4];
#pragma unroll
    for (int qt = 0; qt < 2; ++qt)
#pragma unroll
        for (int ht = 0; ht < 4; ++ht) oacc[qt][ht] = (f32x4){0.f, 0.f, 0.f, 0.f};
    float psum[2] = {0.f, 0.f};

    const int kr = tid >> 3, kc = tid & 7;
    const int kcc = kc ^ ((kr & 3) ^ (((kr >> 3) & 3) << 1));
    const short* kSrc = Kp + kr * HD + kcc * 8;     // + g*32*HD per block
    const int kDst = kr * 64 + kc * 8;
    const int vr = tid >> 2, vc = tid & 3;
    const int vcc = vc ^ ((vr >> 1) & 3);
    const short* vSrc = Vp + vr * SEQ + vcc * 8;    // + g*32 per block
    const int vDst = 2048 + vr * 32 + vc * 8;

#define STAGE(bf, g) do {                                   \
        async16(kSrc + (g) * (32 * HD), &lds[bf][kDst]);    \
        async16(vSrc + (g) * 32, &lds[bf][vDst]);           \
    } while (0)

    const int rA = 8 * (l15 >> 2) + (l15 & 3);
    const int sk = (l15 & 3) ^ ((l15 >> 2) << 1);
    const int offK = rA * 64 + ((quad ^ sk) * 8);
    const int offV = 2048 + l15 * 32 + ((quad ^ ((l15 >> 1) & 3)) * 8);

    STAGE(0, 0); STAGE(1, 1); STAGE(2, 2);   // 3-deep prologue

    for (int g = 0; g < 32; ++g) {
        if (g <= 29)      asm volatile("s_waitcnt vmcnt(4)" ::: "memory");
        else if (g == 30) asm volatile("s_waitcnt vmcnt(2)" ::: "memory");
        else              asm volatile("s_waitcnt vmcnt(0)" ::: "memory");
        __builtin_amdgcn_s_barrier();
        if (g < 29) STAGE((g + 3) & 3, g + 3);

        const short* kb = &lds[g & 3][0];
        f16x8 kA0 = ldfragh(kb + offK);
        f16x8 kA1 = ldfragh(kb + (offK ^ 32));
        f16x8 kB0 = ldfragh(kb + offK + 256);
        f16x8 kB1 = ldfragh(kb + (offK ^ 32) + 256);
        f16x8 v0 = ldfragh(kb + offV);
        f16x8 v1 = ldfragh(kb + offV + 512);
        f16x8 v2 = ldfragh(kb + offV + 1024);
        f16x8 v3 = ldfragh(kb + offV + 1536);

        __builtin_amdgcn_s_setprio(1);
#pragma unroll
        for (int qt = 0; qt < 2; ++qt) {
            f32x4 sA = (f32x4){0.f, 0.f, 0.f, 0.f};
            sA = mfma32h(kA0, qf[qt][0], sA);
            sA = mfma32h(kA1, qf[qt][1], sA);
            f32x4 sB = (f32x4){0.f, 0.f, 0.f, 0.f};
            sB = mfma32h(kB0, qf[qt][0], sB);
            sB = mfma32h(kB1, qf[qt][1], sB);
            float eA0 = __builtin_amdgcn_exp2f(sA[0]);
            float eA1 = __builtin_amdgcn_exp2f(sA[1]);
            float eA2 = __builtin_amdgcn_exp2f(sA[2]);
            float eA3 = __builtin_amdgcn_exp2f(sA[3]);
            float eB0 = __builtin_amdgcn_exp2f(sB[0]);
            float eB1 = __builtin_amdgcn_exp2f(sB[1]);
            float eB2 = __builtin_amdgcn_exp2f(sB[2]);
            float eB3 = __builtin_amdgcn_exp2f(sB[3]);
            psum[qt] += ((eA0 + eA1) + (eA2 + eA3)) + ((eB0 + eB1) + (eB2 + eB3));
            U8 u;
            u.h2[0] = __builtin_amdgcn_cvt_pkrtz(eA0, eA1);
            u.h2[1] = __builtin_amdgcn_cvt_pkrtz(eA2, eA3);
            u.h2[2] = __builtin_amdgcn_cvt_pkrtz(eB0, eB1);
            u.h2[3] = __builtin_amdgcn_cvt_pkrtz(eB2, eB3);
            oacc[qt][0] = mfma32h(v0, u.v, oacc[qt][0]);
            oacc[qt][1] = mfma32h(v1, u.v, oacc[qt][1]);
            oacc[qt][2] = mfma32h(v2, u.v, oacc[qt][2]);
            oacc[qt][3] = mfma32h(v3, u.v, oacc[qt][3]);
        }
        __builtin_amdgcn_s_setprio(0);
    }
#undef STAGE

#pragma unroll
    for (int qt = 0; qt < 2; ++qt) {
        psum[qt] += __shfl_xor(psum[qt], 16);
        psum[qt] += __shfl_xor(psum[qt], 32);
    }

#pragma unroll
    for (int qt = 0; qt < 2; ++qt) {
        float rinv = 1.0f / psum[qt];
        short* orow = &O[((size_t)b * SEQ + q0 + qt * 16 + l15) * DIM + h * HD + quad * 4];
#pragma unroll
        for (int ht = 0; ht < 4; ++ht) {
            U4 u;
            u.h2[0] = __builtin_amdgcn_cvt_pkrtz(oacc[qt][ht][0] * rinv, oacc[qt][ht][1] * rinv);
            u.h2[1] = __builtin_amdgcn_cvt_pkrtz(oacc[qt][ht][2] * rinv, oacc[qt][ht][3] * rinv);
            *(f16x4*)(orow + ht * 16) = u.v;
        }
    }
}

extern "C" void kernel_launch(void* const* d_in, const int* in_sizes, int n_in,
                              void* d_out, int out_size, void* d_ws, size_t ws_size,
                              hipStream_t stream) {
    const float* x      = (const float*)d_in[0];
    const float* w_qkv  = (const float*)d_in[1];
    const float* w_proj = (const float*)d_in[2];
    const float* b_proj = (const float*)d_in[3];
    float* out = (float*)d_out;

    short* p = (short*)d_ws;
    short* Xb  = p; p += (size_t)M_TOTAL * DIM;
    short* Wqb = p; p += (size_t)QKV_OUT * DIM;
    short* Wpb = p; p += (size_t)DIM * DIM;
    short* Qb  = p; p += (size_t)B_SZ * NH * SEQ * HD;
    short* Kb  = p; p += (size_t)B_SZ * NH * SEQ * HD;
    short* Vtb = p; p += (size_t)B_SZ * NH * SEQ * HD;   // transposed [b][h][hd][n]
    short* Ob  = p; p += (size_t)M_TOTAL * DIM;

    cvt_kernel<<<1024, 256, 0, stream>>>(x, w_qkv, w_proj, Xb, Wqb, Wpb);
    gemm_bt<0, QKV_OUT, DIM><<<dim3(QKV_OUT / 256, M_TOTAL / 256), 512, 0, stream>>>(
        Xb, Wqb, Qb, Kb, Vtb, nullptr, nullptr);
    attn_kernel<<<B_SZ * NH * (SEQ / 128), 256, 0, stream>>>(Qb, Kb, Vtb, Ob);
    gemm_bt<1, DIM, DIM><<<dim3(DIM / 256, M_TOTAL / 256), 512, 0, stream>>>(
        Ob, Wpb, nullptr, nullptr, nullptr, out, b_proj);
}